// Round 3
// baseline (157.379 us; speedup 1.0000x reference)
//
#include <hip/hip_runtime.h>
#include <math.h>

#define N_WL 262144

#define T_REF 273.15
#define P_REF 101325.0
#define C_LIGHT 299792458.0
#define K_B 1.380649e-23
#define N_AVO 6.02214076e+23

__constant__ float c_nu0[10]  = {254.0f, 280.0f, 310.0f, 940.0f, 1130.0f, 1380.0f, 1400.0f, 1600.0f, 2000.0f, 2700.0f};
__constant__ float c_str[10]  = {1.15e-17f, 5e-18f, 1.9e-19f, 2.5e-23f, 8.2e-24f, 1.8e-22f, 3.5e-25f, 7.8e-26f, 4.2e-24f, 1.2e-24f};
__constant__ float c_wid[10]  = {2.0f, 3.0f, 2.5f, 3.0f, 2.5f, 4.0f, 3.0f, 2.5f, 4.0f, 3.5f};
__constant__ float c_texp[10] = {0.05f, 0.04f, 0.03f, 0.4f, 0.35f, 0.45f, 0.5f, 0.48f, 0.52f, 0.49f};
__constant__ float c_mass[10] = {48.f, 48.f, 48.f, 18.f, 18.f, 18.f, 44.f, 44.f, 44.f, 44.f};
__constant__ int   c_cidx[10] = {0, 0, 0, 1, 1, 1, 2, 2, 2, 2};

// shared-param layout: [0:64] m2, [64:96] h, [96:106] nu0,
// [106:116] inv_sigma, [116:126] y, [126:136] scale
#define WS_M2    0
#define WS_H     64
#define WS_NU0   96
#define WS_ISIG  106
#define WS_Y     116
#define WS_SCALE 126
#define WS_TOT   136

__device__ __forceinline__ float siluf(float x)     { return x / (1.0f + __expf(-x)); }
__device__ __forceinline__ float sigmoidf(float x)  { return 1.0f / (1.0f + __expf(-x)); }
__device__ __forceinline__ float softplusf(float x) { return fmaxf(x, 0.0f) + log1pf(expf(-fabsf(x))); }

// Humlicek-style branched w(x,y) matching the reference (real part only).
__device__ __forceinline__ float voigt_w(float x, float y) {
    float ax = fabsf(x);
    float s  = ax + y;
    if (s >= 15.0f) {
        float ur = y * y - x * x;
        float ui = -2.0f * x * y;
        float dr = 0.5f + ur, di = ui;
        float nr = 0.5641896f * y, ni = 0.5641896f * (-x);
        float den = dr * dr + di * di;
        return (nr * dr + ni * di) / den;
    } else if (ax >= 5.5f) {
        float ur = y * y - x * x;
        float ui = -2.0f * x * y;
        float pr = 1.410474f + 0.5641896f * ur;
        float pi_ = 0.5641896f * ui;
        float tr = y, ti = -x;
        float nr = tr * pr - ti * pi_;
        float ni = tr * pi_ + ti * pr;
        float u2r = ur * ur - ui * ui;
        float u2i = 2.0f * ur * ui;
        float dr = 0.75f + 3.0f * ur + u2r;
        float di = 3.0f * ui + u2i;
        float den = dr * dr + di * di;
        return (nr * dr + ni * di) / den;
    } else {
        float x2 = x * x;
        return expf(-x2) * cosf(2.0f * x * y) * 0.5641895835477563f
             + (2.0f * y / 3.14159265358979f) * sinf(x2) / (x2 + y * y + 1e-10f);
    }
}

// --------- single fused kernel: per-block redundant setup + streaming main ---------
// Setup (line params, continuum hidden h, cross[:8], mixing m2) is recomputed by
// every block: ~20 KB of small-weight reads, L2-broadcast; removes the separate
// setup dispatch, its serial launch gap, and the d_ws round-trip.
__global__ __launch_bounds__(256) void GasAbs_fused_kernel(
    const float* __restrict__ wl,
    const float* __restrict__ Tp, const float* __restrict__ Pp,
    const float* __restrict__ o3, const float* __restrict__ h2o, const float* __restrict__ co2,
    const float* __restrict__ mix_w1, const float* __restrict__ mix_b1,
    const float* __restrict__ mix_w2, const float* __restrict__ mix_b2,
    const float* __restrict__ mix_w3, const float* __restrict__ mix_b3,
    const float* __restrict__ cont_w1, const float* __restrict__ cont_b1,
    const float* __restrict__ cont_w2, const float* __restrict__ cont_b2,
    float* __restrict__ out)
{
    __shared__ float sp[WS_TOT];
    __shared__ float s_feat[10];
    __shared__ float s_m1[64];

    const int t = threadIdx.x;

    // ---- phase A: line params (t<10) + continuum hidden layer h (t<32) ----
    if (t < 64) {
        const double T = (double)Tp[0];
        const double P = (double)Pp[0];
        if (t < 10) {
            const float cc[3] = {o3[0], h2o[0], co2[0]};
            double nu0 = (double)c_nu0[t];
            double sT  = (double)c_str[t] * pow(T_REF / (T + 1e-12), (double)c_texp[t]);
            double gL  = (double)c_wid[t] * (P / (P_REF + 1e-12)) * sqrt(T_REF / (T + 1e-12));
            double gD  = nu0 / C_LIGHT * sqrt(2.0 * K_B * T * N_AVO / ((double)c_mass[t] + 1e-12));
            double sig = gD / (sqrt(2.0 * log(2.0)) + 1e-12);
            sp[WS_NU0  + t] = (float)nu0;
            sp[WS_ISIG + t] = (float)(1.0 / (sig + 1e-12));
            sp[WS_Y    + t] = (float)(gL / (sig + 1e-12));
            sp[WS_SCALE+ t] = (float)((double)cc[c_cidx[t]] * sT / (sig * sqrt(M_PI) + 1e-12));
        }
        if (t < 32) {
            float cf[5];
            cf[0] = (float)(T / (T_REF + 1e-12));
            cf[1] = (float)(P / (P_REF + 1e-12));
            cf[2] = h2o[0];
            cf[3] = 1.0f;
            cf[4] = 0.0f;
            float a = cont_b1[t];
            #pragma unroll
            for (int k = 0; k < 5; k++) a += cf[k] * cont_w1[k * 32 + t];
            sp[WS_H + t] = siluf(a);
        }
        if (t == 0) {
            s_feat[0] = (float)(T / (T_REF + 1e-12));
            s_feat[1] = (float)(P / (P_REF + 1e-12));
        }
    }
    __syncthreads();

    // ---- phase B: cross[:8] -> mixing features ----
    if (t < 8) {
        float w = wl[t];
        float c = cont_b2[t];
        #pragma unroll
        for (int j = 0; j < 32; j++) c += sp[WS_H + j] * cont_w2[(size_t)j * N_WL + t];
        float cross = softplusf(c);
        #pragma unroll
        for (int l = 0; l < 10; l++) {
            float x = (w - sp[WS_NU0 + l]) * sp[WS_ISIG + l];
            cross += sp[WS_SCALE + l] * voigt_w(x, sp[WS_Y + l]);
        }
        s_feat[2 + t] = cross;
    }
    __syncthreads();

    // ---- phase C: m1 = silu(feat @ mix_w1 + b1) ----
    if (t < 64) {
        float a = mix_b1[t];
        #pragma unroll
        for (int k = 0; k < 10; k++) a += s_feat[k] * mix_w1[k * 64 + t];
        s_m1[t] = siluf(a);
    }
    __syncthreads();

    // ---- phase D: m2 = silu(m1 @ mix_w2 + b2) ----
    if (t < 64) {
        float a = mix_b2[t];
        #pragma unroll
        for (int k = 0; k < 64; k++) a += s_m1[k] * mix_w2[k * 64 + t];
        sp[WS_M2 + t] = siluf(a);
    }
    __syncthreads();

    // ---- main streaming phase: 4 wavelengths/thread ----
    const int i = (blockIdx.x * 256 + t) * 4;

    const float4 wlv = *reinterpret_cast<const float4*>(wl + i);

    // continuum: h . cont_w2[:, i..i+3] + b2
    float4 c = *reinterpret_cast<const float4*>(cont_b2 + i);
    #pragma unroll
    for (int j = 0; j < 32; j++) {
        float hj = sp[WS_H + j];
        float4 w = *reinterpret_cast<const float4*>(cont_w2 + (size_t)j * N_WL + i);
        c.x = fmaf(hj, w.x, c.x);
        c.y = fmaf(hj, w.y, c.y);
        c.z = fmaf(hj, w.z, c.z);
        c.w = fmaf(hj, w.w, c.w);
    }

    float4 cross;
    cross.x = softplusf(c.x);
    cross.y = softplusf(c.y);
    cross.z = softplusf(c.z);
    cross.w = softplusf(c.w);

    #pragma unroll
    for (int l = 0; l < 10; l++) {
        const float nu0 = sp[WS_NU0 + l];
        const float is  = sp[WS_ISIG + l];
        const float y   = sp[WS_Y + l];
        const float sc  = sp[WS_SCALE + l];
        cross.x = fmaf(sc, voigt_w((wlv.x - nu0) * is, y), cross.x);
        cross.y = fmaf(sc, voigt_w((wlv.y - nu0) * is, y), cross.y);
        cross.z = fmaf(sc, voigt_w((wlv.z - nu0) * is, y), cross.z);
        cross.w = fmaf(sc, voigt_w((wlv.w - nu0) * is, y), cross.w);
    }

    // mixing gate: sigmoid(m2 . mix_w3[:, i..i+3] + b3)
    float4 m = *reinterpret_cast<const float4*>(mix_b3 + i);
    #pragma unroll
    for (int j = 0; j < 64; j++) {
        float mj = sp[WS_M2 + j];
        float4 w = *reinterpret_cast<const float4*>(mix_w3 + (size_t)j * N_WL + i);
        m.x = fmaf(mj, w.x, m.x);
        m.y = fmaf(mj, w.y, m.y);
        m.z = fmaf(mj, w.z, m.z);
        m.w = fmaf(mj, w.w, m.w);
    }

    float4 o;
    o.x = cross.x * (0.95f + 0.1f * sigmoidf(m.x));
    o.y = cross.y * (0.95f + 0.1f * sigmoidf(m.y));
    o.z = cross.z * (0.95f + 0.1f * sigmoidf(m.z));
    o.w = cross.w * (0.95f + 0.1f * sigmoidf(m.w));
    *reinterpret_cast<float4*>(out + i) = o;
}

extern "C" void kernel_launch(void* const* d_in, const int* in_sizes, int n_in,
                              void* d_out, int out_size, void* d_ws, size_t ws_size,
                              hipStream_t stream) {
    const float* wl      = (const float*)d_in[0];
    const float* Tp      = (const float*)d_in[1];
    const float* Pp      = (const float*)d_in[2];
    const float* o3      = (const float*)d_in[3];
    const float* h2o     = (const float*)d_in[4];
    const float* co2     = (const float*)d_in[5];
    const float* mix_w1  = (const float*)d_in[6];
    const float* mix_b1  = (const float*)d_in[7];
    const float* mix_w2  = (const float*)d_in[8];
    const float* mix_b2  = (const float*)d_in[9];
    const float* mix_w3  = (const float*)d_in[10];
    const float* mix_b3  = (const float*)d_in[11];
    const float* cont_w1 = (const float*)d_in[12];
    const float* cont_b1 = (const float*)d_in[13];
    const float* cont_w2 = (const float*)d_in[14];
    const float* cont_b2 = (const float*)d_in[15];
    float* out = (float*)d_out;

    const int threads = 256;
    const int blocks  = N_WL / (threads * 4);  // 256
    GasAbs_fused_kernel<<<blocks, threads, 0, stream>>>(
        wl, Tp, Pp, o3, h2o, co2,
        mix_w1, mix_b1, mix_w2, mix_b2,
        mix_w3, mix_b3,
        cont_w1, cont_b1, cont_w2, cont_b2,
        out);
}

// Round 4
// 152.291 us; speedup vs baseline: 1.0334x; 1.0334x over previous
//
#include <hip/hip_runtime.h>
#include <math.h>

#define N_WL 262144

#define T_REF 273.15
#define P_REF 101325.0
#define C_LIGHT 299792458.0
#define K_B 1.380649e-23
#define N_AVO 6.02214076e+23

__constant__ float c_nu0[10]  = {254.0f, 280.0f, 310.0f, 940.0f, 1130.0f, 1380.0f, 1400.0f, 1600.0f, 2000.0f, 2700.0f};
__constant__ float c_str[10]  = {1.15e-17f, 5e-18f, 1.9e-19f, 2.5e-23f, 8.2e-24f, 1.8e-22f, 3.5e-25f, 7.8e-26f, 4.2e-24f, 1.2e-24f};
__constant__ float c_wid[10]  = {2.0f, 3.0f, 2.5f, 3.0f, 2.5f, 4.0f, 3.0f, 2.5f, 4.0f, 3.5f};
__constant__ float c_texp[10] = {0.05f, 0.04f, 0.03f, 0.4f, 0.35f, 0.45f, 0.5f, 0.48f, 0.52f, 0.49f};
__constant__ float c_mass[10] = {48.f, 48.f, 48.f, 18.f, 18.f, 18.f, 44.f, 44.f, 44.f, 44.f};
__constant__ int   c_cidx[10] = {0, 0, 0, 1, 1, 1, 2, 2, 2, 2};

// workspace layout (floats): [0:64] m2, [64:96] h, [96:106] nu0,
// [106:116] inv_sigma, [116:126] y, [126:136] scale
#define WS_M2    0
#define WS_H     64
#define WS_NU0   96
#define WS_ISIG  106
#define WS_Y     116
#define WS_SCALE 126
#define WS_TOT   136

__device__ __forceinline__ float siluf(float x)     { return x / (1.0f + __expf(-x)); }
__device__ __forceinline__ float sigmoidf(float x)  { return 1.0f / (1.0f + __expf(-x)); }
__device__ __forceinline__ float softplusf(float x) { return fmaxf(x, 0.0f) + log1pf(expf(-fabsf(x))); }

// Humlicek-style branched w(x,y) matching the reference (real part only).
__device__ __forceinline__ float voigt_w(float x, float y) {
    float ax = fabsf(x);
    float s  = ax + y;
    if (s >= 15.0f) {
        float ur = y * y - x * x;
        float ui = -2.0f * x * y;
        float dr = 0.5f + ur, di = ui;
        float nr = 0.5641896f * y, ni = 0.5641896f * (-x);
        float den = dr * dr + di * di;
        return (nr * dr + ni * di) / den;
    } else if (ax >= 5.5f) {
        float ur = y * y - x * x;
        float ui = -2.0f * x * y;
        float pr = 1.410474f + 0.5641896f * ur;
        float pi_ = 0.5641896f * ui;
        float tr = y, ti = -x;
        float nr = tr * pr - ti * pi_;
        float ni = tr * pi_ + ti * pr;
        float u2r = ur * ur - ui * ui;
        float u2i = 2.0f * ur * ui;
        float dr = 0.75f + 3.0f * ur + u2r;
        float di = 3.0f * ui + u2i;
        float den = dr * dr + di * di;
        return (nr * dr + ni * di) / den;
    } else {
        float x2 = x * x;
        return expf(-x2) * cosf(2.0f * x * y) * 0.5641895835477563f
             + (2.0f * y / 3.14159265358979f) * sinf(x2) / (x2 + y * y + 1e-10f);
    }
}

// ---------------- kernel 1: scalar setup (1 block, 64 threads) ----------------
__global__ void GasAbs_setup_kernel(
    const float* __restrict__ wl,
    const float* __restrict__ Tp, const float* __restrict__ Pp,
    const float* __restrict__ o3, const float* __restrict__ h2o, const float* __restrict__ co2,
    const float* __restrict__ mix_w1, const float* __restrict__ mix_b1,
    const float* __restrict__ mix_w2, const float* __restrict__ mix_b2,
    const float* __restrict__ cont_w1, const float* __restrict__ cont_b1,
    const float* __restrict__ cont_w2, const float* __restrict__ cont_b2,
    float* __restrict__ ws)
{
    __shared__ float sp[WS_TOT];
    __shared__ float s_feat[10];
    __shared__ float s_m1[64];

    const int t = threadIdx.x;
    const double T = (double)Tp[0];
    const double P = (double)Pp[0];
    const float  cc[3] = {o3[0], h2o[0], co2[0]};

    if (t < 10) {
        double nu0 = (double)c_nu0[t];
        double sT  = (double)c_str[t] * pow(T_REF / (T + 1e-12), (double)c_texp[t]);
        double gL  = (double)c_wid[t] * (P / (P_REF + 1e-12)) * sqrt(T_REF / (T + 1e-12));
        double gD  = nu0 / C_LIGHT * sqrt(2.0 * K_B * T * N_AVO / ((double)c_mass[t] + 1e-12));
        double sig = gD / (sqrt(2.0 * log(2.0)) + 1e-12);
        sp[WS_NU0  + t] = (float)nu0;
        sp[WS_ISIG + t] = (float)(1.0 / (sig + 1e-12));
        sp[WS_Y    + t] = (float)(gL / (sig + 1e-12));
        sp[WS_SCALE+ t] = (float)((double)cc[c_cidx[t]] * sT / (sig * sqrt(M_PI) + 1e-12));
    }
    if (t < 32) {
        float cf[5];
        cf[0] = (float)(T / (T_REF + 1e-12));
        cf[1] = (float)(P / (P_REF + 1e-12));
        cf[2] = cc[1];
        cf[3] = 1.0f;
        cf[4] = 0.0f;
        float a = cont_b1[t];
        #pragma unroll
        for (int k = 0; k < 5; k++) a += cf[k] * cont_w1[k * 32 + t];
        sp[WS_H + t] = siluf(a);
    }
    __syncthreads();

    if (t < 8) {
        float w = wl[t];
        float c = cont_b2[t];
        #pragma unroll
        for (int j = 0; j < 32; j++) c += sp[WS_H + j] * cont_w2[(size_t)j * N_WL + t];
        float cross = softplusf(c);
        #pragma unroll
        for (int l = 0; l < 10; l++) {
            float x = (w - sp[WS_NU0 + l]) * sp[WS_ISIG + l];
            cross += sp[WS_SCALE + l] * voigt_w(x, sp[WS_Y + l]);
        }
        s_feat[2 + t] = cross;
    }
    if (t == 0) {
        s_feat[0] = (float)(T / (T_REF + 1e-12));
        s_feat[1] = (float)(P / (P_REF + 1e-12));
    }
    __syncthreads();

    {
        float a = mix_b1[t];
        #pragma unroll
        for (int k = 0; k < 10; k++) a += s_feat[k] * mix_w1[k * 64 + t];
        s_m1[t] = siluf(a);
    }
    __syncthreads();

    {
        float a = mix_b2[t];
        #pragma unroll
        for (int k = 0; k < 64; k++) a += s_m1[k] * mix_w2[k * 64 + t];
        sp[WS_M2 + t] = siluf(a);
    }
    __syncthreads();

    ws[t] = sp[t];
    if (t < WS_TOT - 64) ws[64 + t] = sp[64 + t];
}

// ------------- kernel 2: per-wavelength main, 1 element/thread -------------
// 262144 threads = 4096 waves = 50% device occupancy (vs 12.5% before).
// Latency-bound fix: MLP scales with wave count; loads are coalesced dwords.
__global__ __launch_bounds__(256) void GasAbs_main_kernel(
    const float* __restrict__ wl,
    const float* __restrict__ mix_w3, const float* __restrict__ mix_b3,
    const float* __restrict__ cont_w2, const float* __restrict__ cont_b2,
    const float* __restrict__ ws,
    float* __restrict__ out)
{
    __shared__ float sp[WS_TOT];
    const int t = threadIdx.x;
    if (t < WS_TOT) sp[t] = ws[t];
    __syncthreads();

    const int i = blockIdx.x * 256 + t;

    const float w = wl[i];

    // continuum: h . cont_w2[:, i] + b2
    float c = cont_b2[i];
    #pragma unroll
    for (int j = 0; j < 32; j++)
        c = fmaf(sp[WS_H + j], cont_w2[(size_t)j * N_WL + i], c);

    float cross = softplusf(c);

    #pragma unroll
    for (int l = 0; l < 10; l++) {
        const float x = (w - sp[WS_NU0 + l]) * sp[WS_ISIG + l];
        cross = fmaf(sp[WS_SCALE + l], voigt_w(x, sp[WS_Y + l]), cross);
    }

    // mixing gate: sigmoid(m2 . mix_w3[:, i] + b3)
    float m = mix_b3[i];
    #pragma unroll
    for (int j = 0; j < 64; j++)
        m = fmaf(sp[WS_M2 + j], mix_w3[(size_t)j * N_WL + i], m);

    out[i] = cross * (0.95f + 0.1f * sigmoidf(m));
}

extern "C" void kernel_launch(void* const* d_in, const int* in_sizes, int n_in,
                              void* d_out, int out_size, void* d_ws, size_t ws_size,
                              hipStream_t stream) {
    const float* wl      = (const float*)d_in[0];
    const float* Tp      = (const float*)d_in[1];
    const float* Pp      = (const float*)d_in[2];
    const float* o3      = (const float*)d_in[3];
    const float* h2o     = (const float*)d_in[4];
    const float* co2     = (const float*)d_in[5];
    const float* mix_w1  = (const float*)d_in[6];
    const float* mix_b1  = (const float*)d_in[7];
    const float* mix_w2  = (const float*)d_in[8];
    const float* mix_b2  = (const float*)d_in[9];
    const float* mix_w3  = (const float*)d_in[10];
    const float* mix_b3  = (const float*)d_in[11];
    const float* cont_w1 = (const float*)d_in[12];
    const float* cont_b1 = (const float*)d_in[13];
    const float* cont_w2 = (const float*)d_in[14];
    const float* cont_b2 = (const float*)d_in[15];
    float* ws  = (float*)d_ws;
    float* out = (float*)d_out;

    GasAbs_setup_kernel<<<1, 64, 0, stream>>>(
        wl, Tp, Pp, o3, h2o, co2,
        mix_w1, mix_b1, mix_w2, mix_b2,
        cont_w1, cont_b1, cont_w2, cont_b2, ws);

    const int threads = 256;
    const int blocks  = N_WL / threads;  // 1024
    GasAbs_main_kernel<<<blocks, threads, 0, stream>>>(
        wl, mix_w3, mix_b3, cont_w2, cont_b2, ws, out);
}